// Round 5
// baseline (81.444 us; speedup 1.0000x reference)
//
#include <hip/hip_runtime.h>

#define NBINS 49
#define NCH   256
#define SLABC 128
#define FH    256
#define FW    256
#define HWSZ  (FH * FW)

typedef float f4 __attribute__((ext_vector_type(4)));

// ---------------- pass 1: transpose one 128-channel slab (B,C,H,W)->(B,HW,128) ----------------
// R5: slab pipeline. Both slabs reuse the SAME 67 MB workspace so slab1's
// stores re-dirty slab0's LLC lines in place -> at most ~67 MB (not 134) of
// xt ever writes back to HBM, and the pool reads its slab LLC-resident.
// x reads stay nontemporal (read-once, don't evict ws from LLC).
#define TD 64
__global__ __launch_bounds__(256) void transpose_slab(
    const float* __restrict__ in,   // (2, 256, 65536)
    float* __restrict__ outT,       // (2, 65536, 128) workspace slab
    int cbase)                      // 0 or 128
{
    __shared__ float tile[TD][TD + 1];
    const int t   = threadIdx.x;
    const int hw0 = blockIdx.x * TD;
    const int c0  = blockIdx.y * TD;   // 0 or 64 within slab
    const int bz  = blockIdx.z;
    const float* A = in   + ((size_t)bz * NCH + (cbase + c0)) * HWSZ;
    float*       B = outT + (size_t)bz * HWSZ * SLABC + c0;

    // read: coalesced along HW (streamed once -> nontemporal)
    const int hwq = (t & 15) * 4;   // 0..60
    const int cr  = t >> 4;         // 0..15
    #pragma unroll
    for (int k = 0; k < 4; ++k) {
        int c = cr + k * 16;
        f4 v = __builtin_nontemporal_load(
                   (const f4*)&A[(size_t)c * HWSZ + hw0 + hwq]);
        tile[c][hwq + 0] = v.x;
        tile[c][hwq + 1] = v.y;
        tile[c][hwq + 2] = v.z;
        tile[c][hwq + 3] = v.w;
    }
    __syncthreads();
    // write: coalesced along C; NORMAL store (must allocate in cache: the pool
    // re-reads it and the next slab re-dirties it in place)
    const int cq  = (t & 15) * 4;
    const int hwr = t >> 4;
    #pragma unroll
    for (int k = 0; k < 4; ++k) {
        int hw = hwr + k * 16;
        f4 v;
        v.x = tile[cq + 0][hw];
        v.y = tile[cq + 1][hw];
        v.z = tile[cq + 2][hw];
        v.w = tile[cq + 3][hw];
        *(f4*)&B[(size_t)(hw0 + hw) * SLABC + cq] = v;
    }
}

// ---------------- pass 2: pool one 128-channel slab, lane = channel ----------------
// R1: coalesced LDS-staged epilogue (write amp 5.3x -> 1x), 199.6 -> 71.0 us.
// R2 LESSON: gather loads must stay UNCONDITIONAL (latency/MLP).
// R4 LESSON: gather is BW-bound, not latency-bound (deeper batching neutral);
// zero-weight corners are duplicate ADDRESSES (rx==0 => l==r), caches dedupe.
// Thread map: ch = tid&127, h2 = tid>>7 (wave-uniform): waves 0,1 do bins
// 0-24, waves 2,3 do bins 25-48. One barrier pair total.
__global__ __launch_bounds__(256, 4) void rroi_pool_slab(
    const float* __restrict__ xt,     // (2, 65536, 128)
    const float* __restrict__ boxes,  // (1024, 5)
    float* __restrict__ out,          // (1024, 256, 7, 7)
    int cbase)                        // 0 or 128
{
    __shared__ int   s_oTL[NBINS], s_oTR[NBINS], s_oBL[NBINS], s_oBR[NBINS];
    __shared__ float s_wlt[NBINS], s_wrt[NBINS], s_wrb[NBINS], s_wlb[NBINS];
    __shared__ __align__(16) float s_stage[SLABC * NBINS];   // 25,088 B

    const int roi = blockIdx.x;
    const int tid = threadIdx.x;
    const int ch  = tid & (SLABC - 1);
    const int h2  = tid >> 7;          // wave-uniform bin half
    const int b   = roi >> 9;

    if (tid < NBINS) {
        const float* bx = boxes + roi * 5;
        // --- exact f32 replication of reference geometry (absmax=0.0 verified) ---
        float cx  = __fmul_rn(bx[0], 0.25f);
        float cy  = __fmul_rn(bx[1], 0.25f);
        float w   = __fmul_rn(bx[2], 0.25f);
        float h   = __fmul_rn(bx[3], 0.25f);
        float ang = __fmul_rn(bx[4], 0.017453292519943295f);
        float ca = (float)cos((double)ang);
        float sa = (float)sin((double)ang);
        float Sx = __fdiv_rn(w, 7.0f);
        float Sy = __fdiv_rn(h, 7.0f);
        const float dx = -3.5f, dy = -3.5f;
        float M00 = __fmul_rn(ca, Sx);
        float M01 = __fmul_rn(sa, Sy);
        float M02 = __fadd_rn(__fadd_rn(__fmul_rn(M00, dx), __fmul_rn(M01, dy)), cx);
        float nsa = -sa;
        float M10 = __fmul_rn(nsa, Sx);
        float M11 = __fmul_rn(ca, Sy);
        float M12 = __fadd_rn(__fadd_rn(__fmul_rn(M10, dx), __fmul_rn(M11, dy)), cy);

        int ph = tid / 7, pw = tid % 7;
        float minX = 1e30f, maxX = -1e30f, minY = 1e30f, maxY = -1e30f;
        #pragma unroll
        for (int o0 = 0; o0 < 2; ++o0) {
            #pragma unroll
            for (int o1 = 0; o1 < 2; ++o1) {
                float px = (float)(pw + o0);
                float py = (float)(ph + o1);
                float Xc = __fadd_rn(__fadd_rn(__fmul_rn(M00, px), __fmul_rn(M01, py)), M02);
                float Yc = __fadd_rn(__fadd_rn(__fmul_rn(M10, px), __fmul_rn(M11, py)), M12);
                minX = fminf(minX, Xc); maxX = fmaxf(maxX, Xc);
                minY = fminf(minY, Yc); maxY = fmaxf(maxY, Yc);
            }
        }
        float leftMost   = fmaxf(rintf(minX), 0.0f);
        float rightMost  = fminf(rintf(maxX), (float)(FW - 1));
        float topMost    = fmaxf(rintf(minY), 0.0f);
        float bottomMost = fminf(rintf(maxY), (float)(FH - 1));
        float bcx = __fmul_rn(__fadd_rn(leftMost, rightMost), 0.5f);
        float bcy = __fmul_rn(__fadd_rn(topMost, bottomMost), 0.5f);
        float fl = floorf(bcx), ft = floorf(bcy);
        int l   = (int)fl;
        int r   = (int)ceilf(bcx);
        int t   = (int)ft;
        int btm = (int)ceilf(bcy);
        float rx = __fsub_rn(bcx, fl);   // exactly 0.0 or 0.5
        float ry = __fsub_rn(bcy, ft);

        bool vl = (unsigned)l   < (unsigned)FW;
        bool vr = (unsigned)r   < (unsigned)FW;
        bool vt = (unsigned)t   < (unsigned)FH;
        bool vb = (unsigned)btm < (unsigned)FH;
        int xl = min(max(l, 0), FW - 1), xr = min(max(r, 0), FW - 1);
        int yt = min(max(t, 0), FH - 1), yb = min(max(btm, 0), FH - 1);

        s_oTL[tid] = yt * FW + xl;
        s_oTR[tid] = yt * FW + xr;
        s_oBL[tid] = yb * FW + xl;
        s_oBR[tid] = yb * FW + xr;
        float w_lt = (1.0f - rx) * (1.0f - ry);
        float w_rt = rx * (1.0f - ry);
        float w_rb = rx * ry;
        float w_lb = (1.0f - rx) * ry;
        s_wlt[tid] = (vt && vl) ? w_lt : 0.0f;
        s_wrt[tid] = (vt && vr) ? w_rt : 0.0f;
        s_wrb[tid] = (vb && vr) ? w_rb : 0.0f;
        s_wlb[tid] = (vb && vl) ? w_lb : 0.0f;
    }
    __syncthreads();

    const float* fb = xt + (size_t)b * HWSZ * SLABC;
    const int bin0 = h2 * 25;
    const int nb   = 25 - h2;          // 25 bins for half 0, 24 for half 1
    float p[25];
    #pragma unroll
    for (int k = 0; k < 25; ++k) {
        if (k < nb) {                  // wave-uniform trip count
            const int bin = bin0 + k;
            // wave-uniform point offsets -> SGPRs (SALU addr, saddr loads)
            int oTL = __builtin_amdgcn_readfirstlane(s_oTL[bin]);
            int oTR = __builtin_amdgcn_readfirstlane(s_oTR[bin]);
            int oBL = __builtin_amdgcn_readfirstlane(s_oBL[bin]);
            int oBR = __builtin_amdgcn_readfirstlane(s_oBR[bin]);
            float wlt = s_wlt[bin], wrt = s_wrt[bin], wrb = s_wrb[bin], wlb = s_wlb[bin];
            float lt = fb[(size_t)oTL * SLABC + ch];   // 64 lanes -> 256B contiguous
            float rt = fb[(size_t)oTR * SLABC + ch];
            float lb = fb[(size_t)oBL * SLABC + ch];
            float rb = fb[(size_t)oBR * SLABC + ch];
            float v = lt * wlt + rt * wrt + rb * wrb + lb * wlb;
            p[k] = fmaxf(v, 0.0f);
        }
    }

    // ---- coalesced epilogue: stage [ch][bin] then straight LDS->global ----
    // per-(ROI,slab) output block = 128*49 dwords, linear index ch*49+bin;
    // halves write disjoint bin ranges -> single barrier.
    float* dst = s_stage + ch * NBINS + bin0;   // stride 49 (odd) -> conflict-free
    #pragma unroll
    for (int k = 0; k < 25; ++k)
        if (k < nb) dst[k] = p[k];
    __syncthreads();

    f4* out4 = (f4*)(out + ((size_t)roi * NCH + cbase) * NBINS);
    const f4* lds4 = (const f4*)s_stage;
    for (int j = tid; j < SLABC * NBINS / 4; j += 256)   // 1568 f4
        __builtin_nontemporal_store(lds4[j], &out4[j]);
}

// ---------------- fallback: proven R0 single-pass kernel ----------------
__global__ __launch_bounds__(256) void rroi_pool_chw(
    const float* __restrict__ x, const float* __restrict__ boxes, float* __restrict__ out)
{
    __shared__ int   s_l[NBINS], s_r[NBINS], s_t[NBINS], s_b[NBINS];
    __shared__ float s_rx[NBINS], s_ry[NBINS];
    const int roi = blockIdx.x, tid = threadIdx.x, b = roi >> 9;
    if (tid < NBINS) {
        const float* bx = boxes + roi * 5;
        float cx  = __fmul_rn(bx[0], 0.25f);
        float cy  = __fmul_rn(bx[1], 0.25f);
        float w   = __fmul_rn(bx[2], 0.25f);
        float h   = __fmul_rn(bx[3], 0.25f);
        float ang = __fmul_rn(bx[4], 0.017453292519943295f);
        float ca = (float)cos((double)ang);
        float sa = (float)sin((double)ang);
        float Sx = __fdiv_rn(w, 7.0f);
        float Sy = __fdiv_rn(h, 7.0f);
        const float dx = -3.5f, dy = -3.5f;
        float M00 = __fmul_rn(ca, Sx);
        float M01 = __fmul_rn(sa, Sy);
        float M02 = __fadd_rn(__fadd_rn(__fmul_rn(M00, dx), __fmul_rn(M01, dy)), cx);
        float nsa = -sa;
        float M10 = __fmul_rn(nsa, Sx);
        float M11 = __fmul_rn(ca, Sy);
        float M12 = __fadd_rn(__fadd_rn(__fmul_rn(M10, dx), __fmul_rn(M11, dy)), cy);
        int ph = tid / 7, pw = tid % 7;
        float minX = 1e30f, maxX = -1e30f, minY = 1e30f, maxY = -1e30f;
        #pragma unroll
        for (int o0 = 0; o0 < 2; ++o0)
            #pragma unroll
            for (int o1 = 0; o1 < 2; ++o1) {
                float px = (float)(pw + o0);
                float py = (float)(ph + o1);
                float Xc = __fadd_rn(__fadd_rn(__fmul_rn(M00, px), __fmul_rn(M01, py)), M02);
                float Yc = __fadd_rn(__fadd_rn(__fmul_rn(M10, px), __fmul_rn(M11, py)), M12);
                minX = fminf(minX, Xc); maxX = fmaxf(maxX, Xc);
                minY = fminf(minY, Yc); maxY = fmaxf(maxY, Yc);
            }
        float leftMost   = fmaxf(rintf(minX), 0.0f);
        float rightMost  = fminf(rintf(maxX), (float)(FW - 1));
        float topMost    = fmaxf(rintf(minY), 0.0f);
        float bottomMost = fminf(rintf(maxY), (float)(FH - 1));
        float bcx = __fmul_rn(__fadd_rn(leftMost, rightMost), 0.5f);
        float bcy = __fmul_rn(__fadd_rn(topMost, bottomMost), 0.5f);
        float fl = floorf(bcx), ft = floorf(bcy);
        s_l[tid] = (int)fl;  s_r[tid] = (int)ceilf(bcx);
        s_t[tid] = (int)ft;  s_b[tid] = (int)ceilf(bcy);
        s_rx[tid] = __fsub_rn(bcx, fl);
        s_ry[tid] = __fsub_rn(bcy, ft);
    }
    __syncthreads();
    const float* featb = x + (size_t)b * NCH * HWSZ;
    float* outr = out + (size_t)roi * NCH * NBINS;
    for (int i = tid; i < NCH * NBINS; i += 256) {
        int c = i / NBINS, bin = i - c * NBINS;
        int l = s_l[bin], r = s_r[bin], t = s_t[bin], btm = s_b[bin];
        float rx = s_rx[bin], ry = s_ry[bin];
        const float* fc = featb + (size_t)c * HWSZ;
        bool vl = (unsigned)l < (unsigned)FW, vr = (unsigned)r < (unsigned)FW;
        bool vt = (unsigned)t < (unsigned)FH, vb = (unsigned)btm < (unsigned)FH;
        int lc = min(max(l, 0), FW - 1), rc = min(max(r, 0), FW - 1);
        int tc = min(max(t, 0), FH - 1), bc = min(max(btm, 0), FH - 1);
        float lt = (vt && vl) ? fc[tc * FW + lc] : 0.0f;
        float rt = (vt && vr) ? fc[tc * FW + rc] : 0.0f;
        float lb = (vb && vl) ? fc[bc * FW + lc] : 0.0f;
        float rb = (vb && vr) ? fc[bc * FW + rc] : 0.0f;
        float w_lt = (1.0f - rx) * (1.0f - ry);
        float w_rt = rx * (1.0f - ry);
        float w_rb = rx * ry;
        float w_lb = (1.0f - rx) * ry;
        float v = lt * w_lt + rt * w_rt + rb * w_rb + lb * w_lb;
        outr[i] = fmaxf(v, 0.0f);
    }
}

extern "C" void kernel_launch(void* const* d_in, const int* in_sizes, int n_in,
                              void* d_out, int out_size, void* d_ws, size_t ws_size,
                              hipStream_t stream) {
    const float* x     = (const float*)d_in[0];
    const float* boxes = (const float*)d_in[1];
    float* out = (float*)d_out;
    (void)in_sizes; (void)n_in; (void)out_size;

    const size_t need_slab = (size_t)2 * HWSZ * SLABC * sizeof(float);  // 67.1 MB
    if (ws_size >= need_slab) {
        float* xts = (float*)d_ws;   // one slab, reused by both passes
        for (int s = 0; s < 2; ++s) {
            transpose_slab<<<dim3(HWSZ / TD, SLABC / TD, 2), dim3(256), 0, stream>>>(
                x, xts, s * SLABC);
            rroi_pool_slab<<<dim3(1024), dim3(256), 0, stream>>>(
                xts, boxes, out, s * SLABC);
        }
    } else {
        rroi_pool_chw<<<dim3(1024), dim3(256), 0, stream>>>(x, boxes, out);
    }
}